// Round 12
// baseline (207.281 us; speedup 1.0000x reference)
//
#include <hip/hip_runtime.h>

// Problem constants (hardcoded; shapes are fixed by the reference).
#define BATCH 4
#define SQ 2048
#define SKV 2048
#define DMODEL 1024
#define HEADS 16
#define DH 64

typedef __bf16 bf8_t __attribute__((ext_vector_type(8)));
typedef float f4_t __attribute__((ext_vector_type(4)));
typedef float f16_t __attribute__((ext_vector_type(16)));
typedef unsigned int u32;
typedef unsigned short ush;

static __device__ __forceinline__ ush f2bf(float f) {
  __bf16 h = (__bf16)f;
  return __builtin_bit_cast(ush, h);
}
static __device__ __forceinline__ u32 pk2(float a, float b) {
  return (u32)f2bf(a) | ((u32)f2bf(b) << 16);
}
// async global->LDS, 16B per lane. dst = wave-uniform base; HW adds lane*16.
static __device__ __forceinline__ void async16(const ush* g, ush* l) {
  __builtin_amdgcn_global_load_lds((const __attribute__((address_space(1))) unsigned int*)g,
                                   (__attribute__((address_space(3))) unsigned int*)l, 16, 0, 0);
}
// raw barrier with compiler memory fences on both sides
static __device__ __forceinline__ void barrier_f() {
  asm volatile("" ::: "memory");
  __builtin_amdgcn_s_barrier();
  asm volatile("" ::: "memory");
}

// ---------------------------------------------------------------------------
// prep: fused activation cvt (blocks 0..8191) + weight transpose (8192..9215).
// ---------------------------------------------------------------------------
__global__ __launch_bounds__(256) void prep_k(const float* __restrict__ hs,
                                              const float* __restrict__ ehs,
                                              const float* __restrict__ W0,
                                              const float* __restrict__ W1,
                                              const float* __restrict__ W2,
                                              const float* __restrict__ W3,
                                              ush* __restrict__ wT,
                                              ush* __restrict__ hsb, ush* __restrict__ ehsb) {
  __shared__ ush t[64][72];
  const int bx = blockIdx.x;
  const int tid = threadIdx.x;
  if (bx < 8192) {
    const float* X = bx < 4096 ? hs : ehs;
    ush* Y = bx < 4096 ? hsb : ehsb;
    const size_t i = ((size_t)(bx & 4095) * 256 + tid) * 8;
    float4 a = *reinterpret_cast<const float4*>(X + i);
    float4 b = *reinterpret_cast<const float4*>(X + i + 4);
    uint4 u = {pk2(a.x, a.y), pk2(a.z, a.w), pk2(b.x, b.y), pk2(b.z, b.w)};
    *reinterpret_cast<uint4*>(Y + i) = u;
    return;
  }
  const int idx = bx - 8192;  // 0..1023
  const int z = idx >> 8, kb = (idx >> 4) & 15, nb = idx & 15;
  const float* W = z == 0 ? W0 : z == 1 ? W1 : z == 2 ? W2 : W3;
  const float scl = (z == 0) ? 0.125f * 1.44269504088896f : 1.0f;
  ush* o = wT + (size_t)z * (DMODEL * DMODEL);
  const int k0 = kb * 64, n0 = nb * 64;
#pragma unroll
  for (int it = 0; it < 4; ++it) {
    int c = tid + it * 256;
    int r = c >> 4, q4 = c & 15;
    float4 v = *reinterpret_cast<const float4*>(&W[(size_t)(k0 + r) * DMODEL + n0 + q4 * 4]);
    t[q4 * 4 + 0][r] = f2bf(v.x * scl);
    t[q4 * 4 + 1][r] = f2bf(v.y * scl);
    t[q4 * 4 + 2][r] = f2bf(v.z * scl);
    t[q4 * 4 + 3][r] = f2bf(v.w * scl);
  }
  __syncthreads();
#pragma unroll
  for (int it = 0; it < 2; ++it) {
    int c = tid + it * 256;
    int r = c >> 3, s8 = c & 7;
    uint4 pv;
    pv.x = (u32)t[r][s8 * 8 + 0] | ((u32)t[r][s8 * 8 + 1] << 16);
    pv.y = (u32)t[r][s8 * 8 + 2] | ((u32)t[r][s8 * 8 + 3] << 16);
    pv.z = (u32)t[r][s8 * 8 + 4] | ((u32)t[r][s8 * 8 + 5] << 16);
    pv.w = (u32)t[r][s8 * 8 + 6] | ((u32)t[r][s8 * 8 + 7] << 16);
    *reinterpret_cast<uint4*>(&o[(size_t)(n0 + r) * DMODEL + k0 + s8 * 8]) = pv;
  }
}

// ---------------------------------------------------------------------------
// Projection GEMM, 128x128 tile, BK=64, global_load_lds staging, double-
// buffered, counted vmcnt. seg1/seg2 epilogues route through LDS (reusing As)
// so K2/V2 global writes are fully coalesced: each 128x128 tile = exactly 4
// contiguous 4096-elem chunks; each thread streams 2x uint4 per chunk.
//   0: A=hsb  -> Qb bf16 [row][col]
//   1: A=ehsb -> K2: attn read-order
//   2: A=ehsb -> V2: attn read-order
//   3: A=AO   -> out f32 + bias
// ---------------------------------------------------------------------------
__global__ __launch_bounds__(256, 2) void proj_k(const ush* __restrict__ hsb,
                                                 const ush* __restrict__ ehsb,
                                                 const ush* __restrict__ AO,
                                                 const ush* __restrict__ wT,
                                                 ush* __restrict__ Qb, ush* __restrict__ K2,
                                                 ush* __restrict__ V2, float* __restrict__ out,
                                                 const float* __restrict__ bias, int segbase) {
  __shared__ ush As[2][128 * 64];
  __shared__ ush Bs[2][128 * 64];
  const int tid = threadIdx.x;
  const int lane = tid & 63, w = tid >> 6;
  const int wr = w >> 1, wc = w & 1;
  const int lr = lane & 15, lg = lane >> 4;
  const int bid = blockIdx.x;
  const int seg = segbase + (bid >> 9);
  const int t = bid & 511;
  const int m0 = (t >> 3) * 128, n0 = (t & 7) * 128;
  const ush* A = seg == 0 ? hsb : (seg == 3 ? AO : ehsb);
  const ush* BT = wT + (size_t)seg * (DMODEL * DMODEL);

  auto stage = [&](int bf, int kt) {
    const int kb = kt * 64;
#pragma unroll
    for (int ch = 0; ch < 4; ++ch) {
      const int g = ch * 256 + tid;
      const int r = g >> 3, s8 = (g & 7) ^ (r & 7);
      async16(A + (size_t)(m0 + r) * DMODEL + kb + s8 * 8, &As[bf][(ch * 256 + w * 64) * 8]);
      async16(BT + (size_t)(n0 + r) * DMODEL + kb + s8 * 8, &Bs[bf][(ch * 256 + w * 64) * 8]);
    }
  };

  f4_t acc[4][4] = {};
  stage(0, 0);
  for (int kt = 0; kt < DMODEL / 64; ++kt) {
    const int cur = kt & 1;
    barrier_f();
    if (kt + 1 < DMODEL / 64) {
      stage(cur ^ 1, kt + 1);
      asm volatile("s_waitcnt vmcnt(8)" ::: "memory");
    } else {
      asm volatile("s_waitcnt vmcnt(0)" ::: "memory");
    }
    barrier_f();
#pragma unroll
    for (int ks = 0; ks < 2; ++ks) {
      bf8_t a[4], b[4];
#pragma unroll
      for (int rf = 0; rf < 4; ++rf) {
        const int row = wr * 64 + rf * 16 + lr;
        a[rf] = *reinterpret_cast<const bf8_t*>(
            &As[cur][(row * 64 + ks * 32 + lg * 8) ^ ((row & 7) << 3)]);
      }
#pragma unroll
      for (int cf = 0; cf < 4; ++cf) {
        const int nn = wc * 64 + cf * 16 + lr;
        b[cf] = *reinterpret_cast<const bf8_t*>(
            &Bs[cur][(nn * 64 + ks * 32 + lg * 8) ^ ((nn & 7) << 3)]);
      }
      __builtin_amdgcn_s_setprio(1);
#pragma unroll
      for (int rf = 0; rf < 4; ++rf)
#pragma unroll
        for (int cf = 0; cf < 4; ++cf)
          acc[rf][cf] = __builtin_amdgcn_mfma_f32_16x16x32_bf16(a[rf], b[cf], acc[rf][cf], 0, 0, 0);
      __builtin_amdgcn_s_setprio(0);
    }
  }
  // Epilogue. C/D layout: col = lane&15, row = (lane>>4)*4 + i.
  if (seg == 1 || seg == 2) {
    // route through LDS (reuse As: 2x8192 = 16384 ushorts, contiguous)
    ush* L = &As[0][0];
    barrier_f();  // all waves done with As/Bs frag reads
#pragma unroll
    for (int rf = 0; rf < 4; ++rf)
#pragma unroll
      for (int cf = 0; cf < 4; ++cf) {
        const int nl = wc * 64 + cf * 16 + lr;
        const int h2 = nl >> 6, dd = nl & 63;
#pragma unroll
        for (int i = 0; i < 4; ++i) {
          const int kvl = wr * 64 + rf * 16 + lg * 4 + i;
          const int kt2 = kvl >> 6, s = kvl & 63;
          int idx;
          if (seg == 1) {
            // K2 chunk layout: (fd*2+hi2)*512 + kvi*8 + e  (d-bits from col)
            idx = ((h2 * 2 + kt2) << 12) + (((dd >> 4) * 2 + ((dd >> 3) & 1)) << 9) +
                  (s << 3) + (dd & 7);
          } else {
            // V2 chunk layout: (ks2*2+hi2)*512 + dd*8 + e0  (kv-bits from row)
            idx = ((h2 * 2 + kt2) << 12) + (((s >> 4) * 2 + ((s >> 3) & 1)) << 9) +
                  (dd << 3) + (s & 7);
          }
          L[idx] = f2bf(acc[rf][cf][i]);
        }
      }
    barrier_f();
    // stream out: 4 chunks x 4096 elems; 16 elems (2x uint4) per thread/chunk
    ush* G = (seg == 1) ? K2 : V2;
    const int bb = m0 >> 11, kt0 = (m0 & 2047) >> 6;
    const int h0 = n0 >> 6;
#pragma unroll
    for (int j = 0; j < 4; ++j) {
      const size_t dst =
          ((size_t)(bb * 16 + h0 + (j >> 1)) * 32 + kt0 + (j & 1)) * 4096 + tid * 16;
      *reinterpret_cast<uint4*>(&G[dst]) =
          *reinterpret_cast<const uint4*>(&L[j * 4096 + tid * 16]);
      *reinterpret_cast<uint4*>(&G[dst + 8]) =
          *reinterpret_cast<const uint4*>(&L[j * 4096 + tid * 16 + 8]);
    }
  } else if (seg == 3) {
#pragma unroll
    for (int cf = 0; cf < 4; ++cf) {
      const int col = n0 + wc * 64 + cf * 16 + lr;
      const float bv = bias[col];
#pragma unroll
      for (int rf = 0; rf < 4; ++rf)
#pragma unroll
        for (int i = 0; i < 4; ++i) {
          const int row = m0 + wr * 64 + rf * 16 + lg * 4 + i;
          out[(size_t)row * DMODEL + col] = acc[rf][cf][i] + bv;
        }
    }
  } else {
#pragma unroll
    for (int rf = 0; rf < 4; ++rf)
#pragma unroll
      for (int cf = 0; cf < 4; ++cf)
#pragma unroll
        for (int i = 0; i < 4; ++i) {
          const int row = m0 + wr * 64 + rf * 16 + lg * 4 + i;
          const int col = n0 + wc * 64 + cf * 16 + lr;
          Qb[(size_t)row * DMODEL + col] = f2bf(acc[rf][cf][i]);
        }
  }
}

// ---------------------------------------------------------------------------
// Flash attention (swapped 32x32, D=64), zero-shift softmax, read-order K/V,
// MFMA ones-trick row-sum. (R7 configuration — measured best, 89.2 us.)
// ---------------------------------------------------------------------------
__global__ __launch_bounds__(256, 4) void attn_k(const ush* __restrict__ Qb,
                                                 const ush* __restrict__ K2,
                                                 const ush* __restrict__ V2,
                                                 ush* __restrict__ AO) {
  __shared__ ush Ks[2][4096];
  __shared__ ush Vs[2][4096];
  const int tid = threadIdx.x;
  const int lane = tid & 63, w = tid >> 6;
  const int rw = lane & 31, hi = lane >> 5;

  const int bid = blockIdx.x;
  const int swz = (bid & 7) * 128 + (bid >> 3);
  const int hl = swz >> 4;  // b*16+h
  const int qb = swz & 15;
  const int b = hl >> 4, h = hl & 15;
  const int q0 = qb * 128 + w * 32;

  const ush* Qp = Qb + ((size_t)(b * SQ + q0 + rw)) * DMODEL + h * DH + hi * 8;
  bf8_t qf[4];
#pragma unroll
  for (int f = 0; f < 4; ++f) qf[f] = *reinterpret_cast<const bf8_t*>(Qp + 16 * f);

  bf8_t ones;
#pragma unroll
  for (int i = 0; i < 8; ++i) ones[i] = __builtin_bit_cast(__bf16, (ush)0x3F80);

  f16_t acc0 = {}, acc1 = {}, sacc = {};

  const ush* Kh = K2 + (size_t)hl * 131072;  // 32 kt * 4096
  const ush* Vh = V2 + (size_t)hl * 131072;

  auto stage = [&](int bf, int kt) {  // 4 async16 per wave, pure linear copy
    const ush* ksrc = Kh + (size_t)kt * 4096;
    const ush* vsrc = Vh + (size_t)kt * 4096;
#pragma unroll
    for (int ch = 0; ch < 2; ++ch) {
      const int off = (ch * 256 + tid) * 8;
      async16(ksrc + off, &Ks[bf][(ch * 256 + w * 64) * 8]);
      async16(vsrc + off, &Vs[bf][(ch * 256 + w * 64) * 8]);
    }
  };

  stage(0, 0);
  int cur = 0;
  for (int kt = 0; kt < SKV / 64; ++kt) {
    barrier_f();
    if (kt + 1 < SKV / 64) {
      stage(cur ^ 1, kt + 1);
      asm volatile("s_waitcnt vmcnt(4)" ::: "memory");
    } else {
      asm volatile("s_waitcnt vmcnt(0)" ::: "memory");
    }
    barrier_f();

    // ---- QK^T: S^T[kv][q] (zero shift) ----
    f16_t s0 = {}, s1 = {};
    __builtin_amdgcn_s_setprio(1);
#pragma unroll
    for (int f = 0; f < 4; ++f) {
      const int base = (f * 128 + hi * 64 + rw) * 8;
      bf8_t k0 = *reinterpret_cast<const bf8_t*>(&Ks[cur][base]);
      bf8_t k1 = *reinterpret_cast<const bf8_t*>(&Ks[cur][base + 256]);
      s0 = __builtin_amdgcn_mfma_f32_32x32x16_bf16(k0, qf[f], s0, 0, 0, 0);
      s1 = __builtin_amdgcn_mfma_f32_32x32x16_bf16(k1, qf[f], s1, 0, 0, 0);
    }
    __builtin_amdgcn_s_setprio(0);

    // ---- P = exp2(S) ----
#pragma unroll
    for (int i = 0; i < 16; ++i) s0[i] = __builtin_amdgcn_exp2f(s0[i]);
#pragma unroll
    for (int i = 0; i < 16; ++i) s1[i] = __builtin_amdgcn_exp2f(s1[i]);

    // ---- PV: O^T += V^T x P; row-sum via MFMA ones-trick ----
    __builtin_amdgcn_s_setprio(1);
#pragma unroll
    for (int kb = 0; kb < 2; ++kb) {
      const f16_t& sv = kb ? s1 : s0;
      bf8_t pf[2];
      {
        u32 w0 = pk2(sv[0], sv[1]), w2 = pk2(sv[4], sv[5]);
        asm volatile("v_permlane32_swap_b32 %0, %1" : "+v"(w0), "+v"(w2));
        u32 w1 = pk2(sv[2], sv[3]), w3 = pk2(sv[6], sv[7]);
        asm volatile("v_permlane32_swap_b32 %0, %1" : "+v"(w1), "+v"(w3));
        uint4 t0 = {w0, w1, w2, w3};
        pf[0] = __builtin_bit_cast(bf8_t, t0);
        u32 x0 = pk2(sv[8], sv[9]), x2 = pk2(sv[12], sv[13]);
        asm volatile("v_permlane32_swap_b32 %0, %1" : "+v"(x0), "+v"(x2));
        u32 x1 = pk2(sv[10], sv[11]), x3 = pk2(sv[14], sv[15]);
        asm volatile("v_permlane32_swap_b32 %0, %1" : "+v"(x1), "+v"(x3));
        uint4 t1 = {x0, x1, x2, x3};
        pf[1] = __builtin_bit_cast(bf8_t, t1);
      }
#pragma unroll
      for (int s = 0; s < 2; ++s) {
        const int vbase = ((2 * kb + s) * 128 + hi * 64 + rw) * 8;
        bf8_t v0 = *reinterpret_cast<const bf8_t*>(&Vs[cur][vbase]);
        bf8_t v1 = *reinterpret_cast<const bf8_t*>(&Vs[cur][vbase + 256]);
        acc0 = __builtin_amdgcn_mfma_f32_32x32x16_bf16(v0, pf[s], acc0, 0, 0, 0);
        acc1 = __builtin_amdgcn_mfma_f32_32x32x16_bf16(v1, pf[s], acc1, 0, 0, 0);
        sacc = __builtin_amdgcn_mfma_f32_32x32x16_bf16(ones, pf[s], sacc, 0, 0, 0);
      }
    }
    __builtin_amdgcn_s_setprio(0);
    cur ^= 1;
  }

  const float inv = 1.f / sacc[0];
  ush* Op = AO + ((size_t)(b * SQ + q0 + rw)) * DMODEL + h * DH;
#pragma unroll
  for (int db = 0; db < 2; ++db) {
    const f16_t& A = db ? acc1 : acc0;
#pragma unroll
    for (int r = 0; r < 16; r += 2) {
      const int d = db * 32 + (r & 3) + 8 * (r >> 2) + 4 * hi;
      *reinterpret_cast<u32*>(Op + d) = pk2(A[r] * inv, A[r + 1] * inv);
    }
  }
}

// ---------------------------------------------------------------------------
extern "C" void kernel_launch(void* const* d_in, const int* in_sizes, int n_in,
                              void* d_out, int out_size, void* d_ws, size_t ws_size,
                              hipStream_t stream) {
  const float* hs = (const float*)d_in[0];
  const float* ehs = (const float*)d_in[1];
  const float* Wq = (const float*)d_in[2];
  const float* Wk = (const float*)d_in[3];
  const float* Wv = (const float*)d_in[4];
  const float* Wo = (const float*)d_in[5];
  const float* bo = (const float*)d_in[6];
  float* out = (float*)d_out;

  unsigned short* ws = (unsigned short*)d_ws;
  const size_t MM = (size_t)1024 * 1024;
  unsigned short* wT = ws;            // 4 MM: WqT(scaled), WkT, WvT, WoT (bf16 [N][K])
  unsigned short* Qb = ws + 4 * MM;   // 8 MM: Q bf16 [row][col]
  unsigned short* K2 = Qb + 8 * MM;   // 8 MM: K bf16, attn read-order
  unsigned short* V2 = K2 + 8 * MM;   // 8 MM: V bf16, attn read-order
  unsigned short* AO = V2 + 8 * MM;   // 8 MM: attn out bf16
  // bf16 activations live inside d_out (32 MB); consumed before final GEMM.
  unsigned short* hsb = (unsigned short*)d_out;  // 8 MM
  unsigned short* ehsb = hsb + 8 * MM;           // 8 MM

  prep_k<<<dim3(9216), 256, 0, stream>>>(hs, ehs, Wq, Wk, Wv, Wo, wT, hsb, ehsb);
  proj_k<<<dim3(1536), 256, 0, stream>>>(hsb, ehsb, AO, wT, Qb, K2, V2, out, bo, 0);
  attn_k<<<dim3(1024), 256, 0, stream>>>(Qb, K2, V2, AO);
  proj_k<<<dim3(512), 256, 0, stream>>>(hsb, ehsb, AO, wT, Qb, K2, V2, out, bo, 3);
}

// Round 13
// 206.571 us; speedup vs baseline: 1.0034x; 1.0034x over previous
//
#include <hip/hip_runtime.h>

// Problem constants (hardcoded; shapes are fixed by the reference).
#define BATCH 4
#define SQ 2048
#define SKV 2048
#define DMODEL 1024
#define HEADS 16
#define DH 64

typedef __bf16 bf8_t __attribute__((ext_vector_type(8)));
typedef float f4_t __attribute__((ext_vector_type(4)));
typedef float f16_t __attribute__((ext_vector_type(16)));
typedef unsigned int u32;
typedef unsigned short ush;

static __device__ __forceinline__ ush f2bf(float f) {
  __bf16 h = (__bf16)f;
  return __builtin_bit_cast(ush, h);
}
static __device__ __forceinline__ u32 pk2(float a, float b) {
  return (u32)f2bf(a) | ((u32)f2bf(b) << 16);
}
// async global->LDS, 16B per lane. dst = wave-uniform base; HW adds lane*16.
static __device__ __forceinline__ void async16(const ush* g, ush* l) {
  __builtin_amdgcn_global_load_lds((const __attribute__((address_space(1))) unsigned int*)g,
                                   (__attribute__((address_space(3))) unsigned int*)l, 16, 0, 0);
}
// raw barrier with compiler memory fences on both sides
static __device__ __forceinline__ void barrier_f() {
  asm volatile("" ::: "memory");
  __builtin_amdgcn_s_barrier();
  asm volatile("" ::: "memory");
}

// ---------------------------------------------------------------------------
// prep: fused activation cvt (blocks 0..8191) + weight transpose (8192..9215).
// ---------------------------------------------------------------------------
__global__ __launch_bounds__(256) void prep_k(const float* __restrict__ hs,
                                              const float* __restrict__ ehs,
                                              const float* __restrict__ W0,
                                              const float* __restrict__ W1,
                                              const float* __restrict__ W2,
                                              const float* __restrict__ W3,
                                              ush* __restrict__ wT,
                                              ush* __restrict__ hsb, ush* __restrict__ ehsb) {
  __shared__ ush t[64][72];
  const int bx = blockIdx.x;
  const int tid = threadIdx.x;
  if (bx < 8192) {
    const float* X = bx < 4096 ? hs : ehs;
    ush* Y = bx < 4096 ? hsb : ehsb;
    const size_t i = ((size_t)(bx & 4095) * 256 + tid) * 8;
    float4 a = *reinterpret_cast<const float4*>(X + i);
    float4 b = *reinterpret_cast<const float4*>(X + i + 4);
    uint4 u = {pk2(a.x, a.y), pk2(a.z, a.w), pk2(b.x, b.y), pk2(b.z, b.w)};
    *reinterpret_cast<uint4*>(Y + i) = u;
    return;
  }
  const int idx = bx - 8192;  // 0..1023
  const int z = idx >> 8, kb = (idx >> 4) & 15, nb = idx & 15;
  const float* W = z == 0 ? W0 : z == 1 ? W1 : z == 2 ? W2 : W3;
  const float scl = (z == 0) ? 0.125f * 1.44269504088896f : 1.0f;
  ush* o = wT + (size_t)z * (DMODEL * DMODEL);
  const int k0 = kb * 64, n0 = nb * 64;
#pragma unroll
  for (int it = 0; it < 4; ++it) {
    int c = tid + it * 256;
    int r = c >> 4, q4 = c & 15;
    float4 v = *reinterpret_cast<const float4*>(&W[(size_t)(k0 + r) * DMODEL + n0 + q4 * 4]);
    t[q4 * 4 + 0][r] = f2bf(v.x * scl);
    t[q4 * 4 + 1][r] = f2bf(v.y * scl);
    t[q4 * 4 + 2][r] = f2bf(v.z * scl);
    t[q4 * 4 + 3][r] = f2bf(v.w * scl);
  }
  __syncthreads();
#pragma unroll
  for (int it = 0; it < 2; ++it) {
    int c = tid + it * 256;
    int r = c >> 3, s8 = c & 7;
    uint4 pv;
    pv.x = (u32)t[r][s8 * 8 + 0] | ((u32)t[r][s8 * 8 + 1] << 16);
    pv.y = (u32)t[r][s8 * 8 + 2] | ((u32)t[r][s8 * 8 + 3] << 16);
    pv.z = (u32)t[r][s8 * 8 + 4] | ((u32)t[r][s8 * 8 + 5] << 16);
    pv.w = (u32)t[r][s8 * 8 + 6] | ((u32)t[r][s8 * 8 + 7] << 16);
    *reinterpret_cast<uint4*>(&o[(size_t)(n0 + r) * DMODEL + k0 + s8 * 8]) = pv;
  }
}

// ---------------------------------------------------------------------------
// Projection GEMM, 128x128 tile, BK=64, global_load_lds staging, double-
// buffered, counted vmcnt. seg1/seg2 epilogues route through LDS so K2/V2
// global writes are fully coalesced. (R12 configuration.)
//   0: A=hsb  -> Qb bf16 [row][col]
//   1: A=ehsb -> K2: attn read-order
//   2: A=ehsb -> V2: attn read-order
//   3: A=AO   -> out f32 + bias
// ---------------------------------------------------------------------------
__global__ __launch_bounds__(256, 2) void proj_k(const ush* __restrict__ hsb,
                                                 const ush* __restrict__ ehsb,
                                                 const ush* __restrict__ AO,
                                                 const ush* __restrict__ wT,
                                                 ush* __restrict__ Qb, ush* __restrict__ K2,
                                                 ush* __restrict__ V2, float* __restrict__ out,
                                                 const float* __restrict__ bias, int segbase) {
  __shared__ ush As[2][128 * 64];
  __shared__ ush Bs[2][128 * 64];
  const int tid = threadIdx.x;
  const int lane = tid & 63, w = tid >> 6;
  const int wr = w >> 1, wc = w & 1;
  const int lr = lane & 15, lg = lane >> 4;
  const int bid = blockIdx.x;
  const int seg = segbase + (bid >> 9);
  const int t = bid & 511;
  const int m0 = (t >> 3) * 128, n0 = (t & 7) * 128;
  const ush* A = seg == 0 ? hsb : (seg == 3 ? AO : ehsb);
  const ush* BT = wT + (size_t)seg * (DMODEL * DMODEL);

  auto stage = [&](int bf, int kt) {
    const int kb = kt * 64;
#pragma unroll
    for (int ch = 0; ch < 4; ++ch) {
      const int g = ch * 256 + tid;
      const int r = g >> 3, s8 = (g & 7) ^ (r & 7);
      async16(A + (size_t)(m0 + r) * DMODEL + kb + s8 * 8, &As[bf][(ch * 256 + w * 64) * 8]);
      async16(BT + (size_t)(n0 + r) * DMODEL + kb + s8 * 8, &Bs[bf][(ch * 256 + w * 64) * 8]);
    }
  };

  f4_t acc[4][4] = {};
  stage(0, 0);
  for (int kt = 0; kt < DMODEL / 64; ++kt) {
    const int cur = kt & 1;
    barrier_f();
    if (kt + 1 < DMODEL / 64) {
      stage(cur ^ 1, kt + 1);
      asm volatile("s_waitcnt vmcnt(8)" ::: "memory");
    } else {
      asm volatile("s_waitcnt vmcnt(0)" ::: "memory");
    }
    barrier_f();
#pragma unroll
    for (int ks = 0; ks < 2; ++ks) {
      bf8_t a[4], b[4];
#pragma unroll
      for (int rf = 0; rf < 4; ++rf) {
        const int row = wr * 64 + rf * 16 + lr;
        a[rf] = *reinterpret_cast<const bf8_t*>(
            &As[cur][(row * 64 + ks * 32 + lg * 8) ^ ((row & 7) << 3)]);
      }
#pragma unroll
      for (int cf = 0; cf < 4; ++cf) {
        const int nn = wc * 64 + cf * 16 + lr;
        b[cf] = *reinterpret_cast<const bf8_t*>(
            &Bs[cur][(nn * 64 + ks * 32 + lg * 8) ^ ((nn & 7) << 3)]);
      }
      __builtin_amdgcn_s_setprio(1);
#pragma unroll
      for (int rf = 0; rf < 4; ++rf)
#pragma unroll
        for (int cf = 0; cf < 4; ++cf)
          acc[rf][cf] = __builtin_amdgcn_mfma_f32_16x16x32_bf16(a[rf], b[cf], acc[rf][cf], 0, 0, 0);
      __builtin_amdgcn_s_setprio(0);
    }
  }
  // Epilogue. C/D layout: col = lane&15, row = (lane>>4)*4 + i.
  if (seg == 1 || seg == 2) {
    ush* L = &As[0][0];
    barrier_f();
#pragma unroll
    for (int rf = 0; rf < 4; ++rf)
#pragma unroll
      for (int cf = 0; cf < 4; ++cf) {
        const int nl = wc * 64 + cf * 16 + lr;
        const int h2 = nl >> 6, dd = nl & 63;
#pragma unroll
        for (int i = 0; i < 4; ++i) {
          const int kvl = wr * 64 + rf * 16 + lg * 4 + i;
          const int kt2 = kvl >> 6, s = kvl & 63;
          int idx;
          if (seg == 1) {
            idx = ((h2 * 2 + kt2) << 12) + (((dd >> 4) * 2 + ((dd >> 3) & 1)) << 9) +
                  (s << 3) + (dd & 7);
          } else {
            idx = ((h2 * 2 + kt2) << 12) + (((s >> 4) * 2 + ((s >> 3) & 1)) << 9) +
                  (dd << 3) + (s & 7);
          }
          L[idx] = f2bf(acc[rf][cf][i]);
        }
      }
    barrier_f();
    ush* G = (seg == 1) ? K2 : V2;
    const int bb = m0 >> 11, kt0 = (m0 & 2047) >> 6;
    const int h0 = n0 >> 6;
#pragma unroll
    for (int j = 0; j < 4; ++j) {
      const size_t dst =
          ((size_t)(bb * 16 + h0 + (j >> 1)) * 32 + kt0 + (j & 1)) * 4096 + tid * 16;
      *reinterpret_cast<uint4*>(&G[dst]) =
          *reinterpret_cast<const uint4*>(&L[j * 4096 + tid * 16]);
      *reinterpret_cast<uint4*>(&G[dst + 8]) =
          *reinterpret_cast<const uint4*>(&L[j * 4096 + tid * 16 + 8]);
    }
  } else if (seg == 3) {
#pragma unroll
    for (int cf = 0; cf < 4; ++cf) {
      const int col = n0 + wc * 64 + cf * 16 + lr;
      const float bv = bias[col];
#pragma unroll
      for (int rf = 0; rf < 4; ++rf)
#pragma unroll
        for (int i = 0; i < 4; ++i) {
          const int row = m0 + wr * 64 + rf * 16 + lg * 4 + i;
          out[(size_t)row * DMODEL + col] = acc[rf][cf][i] + bv;
        }
    }
  } else {
#pragma unroll
    for (int rf = 0; rf < 4; ++rf)
#pragma unroll
      for (int cf = 0; cf < 4; ++cf)
#pragma unroll
        for (int i = 0; i < 4; ++i) {
          const int row = m0 + wr * 64 + rf * 16 + lg * 4 + i;
          const int col = n0 + wc * 64 + cf * 16 + lr;
          Qb[(size_t)row * DMODEL + col] = f2bf(acc[rf][cf][i]);
        }
  }
}

// ---------------------------------------------------------------------------
// Flash attention (swapped 32x32, D=64), zero-shift softmax. NO LDS, NO
// BARRIERS: K/V fragments read directly from L2-resident K2/V2 (read-order
// layouts make per-lane addresses coalesced 1KB/instruction). Waves free-run
// and stagger, overlapping VALU/MFMA/VMEM across the 12 waves/CU.
// Row-sum via VALU 4-chain (no ones-MFMA) to hold VGPR under the (256,3) cap.
// ---------------------------------------------------------------------------
__global__ __launch_bounds__(256, 3) void attn_k(const ush* __restrict__ Qb,
                                                 const ush* __restrict__ K2,
                                                 const ush* __restrict__ V2,
                                                 ush* __restrict__ AO) {
  const int tid = threadIdx.x;
  const int lane = tid & 63, w = tid >> 6;
  const int rw = lane & 31, hi = lane >> 5;

  const int bid = blockIdx.x;
  const int swz = (bid & 7) * 128 + (bid >> 3);
  const int hl = swz >> 4;  // b*16+h ; 8 heads/XCD -> 4MB K+V, L2-resident
  const int qb = swz & 15;
  const int b = hl >> 4, h = hl & 15;
  const int q0 = qb * 128 + w * 32;

  const ush* Qp = Qb + ((size_t)(b * SQ + q0 + rw)) * DMODEL + h * DH + hi * 8;
  bf8_t qf[4];
#pragma unroll
  for (int f = 0; f < 4; ++f) qf[f] = *reinterpret_cast<const bf8_t*>(Qp + 16 * f);

  f16_t acc0 = {}, acc1 = {};
  float lsum = 0.f;

  const int fo = (hi * 64 + rw) * 8;  // lane offset within an f-block
  const ush* Kh = K2 + (size_t)hl * 131072 + fo;  // 32 kt * 4096
  const ush* Vh = V2 + (size_t)hl * 131072 + fo;

  for (int kt = 0; kt < SKV / 64; ++kt) {
    const ush* kp = Kh + kt * 4096;
    const ush* vp = Vh + kt * 4096;

    // ---- K fragments from L2 (8 x dwordx4, coalesced) ----
    bf8_t kf0[4], kf1[4];
#pragma unroll
    for (int f = 0; f < 4; ++f) {
      kf0[f] = *reinterpret_cast<const bf8_t*>(kp + f * 1024);
      kf1[f] = *reinterpret_cast<const bf8_t*>(kp + f * 1024 + 256);
    }
    // ---- V fragments issued early; consumed after exp/pack ----
    bf8_t vf0[4], vf1[4];
#pragma unroll
    for (int g = 0; g < 4; ++g) {
      vf0[g] = *reinterpret_cast<const bf8_t*>(vp + g * 1024);
      vf1[g] = *reinterpret_cast<const bf8_t*>(vp + g * 1024 + 256);
    }

    // ---- QK^T: S^T[kv][q] (zero shift) ----
    f16_t s0 = {}, s1 = {};
    __builtin_amdgcn_s_setprio(1);
#pragma unroll
    for (int f = 0; f < 4; ++f) {
      s0 = __builtin_amdgcn_mfma_f32_32x32x16_bf16(kf0[f], qf[f], s0, 0, 0, 0);
      s1 = __builtin_amdgcn_mfma_f32_32x32x16_bf16(kf1[f], qf[f], s1, 0, 0, 0);
    }
    __builtin_amdgcn_s_setprio(0);

    // ---- P = exp2(S); row-sum via 4 independent chains ----
#pragma unroll
    for (int i = 0; i < 16; ++i) s0[i] = __builtin_amdgcn_exp2f(s0[i]);
#pragma unroll
    for (int i = 0; i < 16; ++i) s1[i] = __builtin_amdgcn_exp2f(s1[i]);
    {
      float t0 = 0.f, t1 = 0.f, t2 = 0.f, t3 = 0.f;
#pragma unroll
      for (int i = 0; i < 16; i += 4) {
        t0 += s0[i];
        t1 += s0[i + 1];
        t2 += s0[i + 2];
        t3 += s0[i + 3];
        t0 += s1[i];
        t1 += s1[i + 1];
        t2 += s1[i + 2];
        t3 += s1[i + 3];
      }
      lsum += (t0 + t1) + (t2 + t3);
    }

    // ---- PV: O^T += V^T x P ----
    __builtin_amdgcn_s_setprio(1);
#pragma unroll
    for (int kb = 0; kb < 2; ++kb) {
      const f16_t& sv = kb ? s1 : s0;
      bf8_t pf[2];
      {
        u32 w0 = pk2(sv[0], sv[1]), w2 = pk2(sv[4], sv[5]);
        asm volatile("v_permlane32_swap_b32 %0, %1" : "+v"(w0), "+v"(w2));
        u32 w1 = pk2(sv[2], sv[3]), w3 = pk2(sv[6], sv[7]);
        asm volatile("v_permlane32_swap_b32 %0, %1" : "+v"(w1), "+v"(w3));
        uint4 t0 = {w0, w1, w2, w3};
        pf[0] = __builtin_bit_cast(bf8_t, t0);
        u32 x0 = pk2(sv[8], sv[9]), x2 = pk2(sv[12], sv[13]);
        asm volatile("v_permlane32_swap_b32 %0, %1" : "+v"(x0), "+v"(x2));
        u32 x1 = pk2(sv[10], sv[11]), x3 = pk2(sv[14], sv[15]);
        asm volatile("v_permlane32_swap_b32 %0, %1" : "+v"(x1), "+v"(x3));
        uint4 t1 = {x0, x1, x2, x3};
        pf[1] = __builtin_bit_cast(bf8_t, t1);
      }
#pragma unroll
      for (int s = 0; s < 2; ++s) {
        const int g = 2 * kb + s;
        acc0 = __builtin_amdgcn_mfma_f32_32x32x16_bf16(vf0[g], pf[s], acc0, 0, 0, 0);
        acc1 = __builtin_amdgcn_mfma_f32_32x32x16_bf16(vf1[g], pf[s], acc1, 0, 0, 0);
      }
    }
    __builtin_amdgcn_s_setprio(0);
  }

  const float lrow = lsum + __shfl_xor(lsum, 32, 64);
  const float inv = 1.f / lrow;
  ush* Op = AO + ((size_t)(b * SQ + q0 + rw)) * DMODEL + h * DH;
#pragma unroll
  for (int db = 0; db < 2; ++db) {
    const f16_t& A = db ? acc1 : acc0;
#pragma unroll
    for (int r = 0; r < 16; r += 2) {
      const int d = db * 32 + (r & 3) + 8 * (r >> 2) + 4 * hi;
      *reinterpret_cast<u32*>(Op + d) = pk2(A[r] * inv, A[r + 1] * inv);
    }
  }
}

// ---------------------------------------------------------------------------
extern "C" void kernel_launch(void* const* d_in, const int* in_sizes, int n_in,
                              void* d_out, int out_size, void* d_ws, size_t ws_size,
                              hipStream_t stream) {
  const float* hs = (const float*)d_in[0];
  const float* ehs = (const float*)d_in[1];
  const float* Wq = (const float*)d_in[2];
  const float* Wk = (const float*)d_in[3];
  const float* Wv = (const float*)d_in[4];
  const float* Wo = (const float*)d_in[5];
  const float* bo = (const float*)d_in[6];
  float* out = (float*)d_out;

  unsigned short* ws = (unsigned short*)d_ws;
  const size_t MM = (size_t)1024 * 1024;
  unsigned short* wT = ws;            // 4 MM: WqT(scaled), WkT, WvT, WoT (bf16 [N][K])
  unsigned short* Qb = ws + 4 * MM;   // 8 MM: Q bf16 [row][col]
  unsigned short* K2 = Qb + 8 * MM;   // 8 MM: K bf16, attn read-order
  unsigned short* V2 = K2 + 8 * MM;   // 8 MM: V bf16, attn read-order
  unsigned short* AO = V2 + 8 * MM;   // 8 MM: attn out bf16
  // bf16 activations live inside d_out (32 MB); consumed before final GEMM.
  unsigned short* hsb = (unsigned short*)d_out;  // 8 MM
  unsigned short* ehsb = hsb + 8 * MM;           // 8 MM

  prep_k<<<dim3(9216), 256, 0, stream>>>(hs, ehs, Wq, Wk, Wv, Wo, wT, hsb, ehsb);
  proj_k<<<dim3(1536), 256, 0, stream>>>(hsb, ehsb, AO, wT, Qb, K2, V2, out, bo, 0);
  attn_k<<<dim3(1024), 256, 0, stream>>>(Qb, K2, V2, AO);
  proj_k<<<dim3(512), 256, 0, stream>>>(hsb, ehsb, AO, wT, Qb, K2, V2, out, bo, 3);
}

// Round 14
// 195.377 us; speedup vs baseline: 1.0609x; 1.0573x over previous
//
#include <hip/hip_runtime.h>

// Problem constants (hardcoded; shapes are fixed by the reference).
#define BATCH 4
#define SQ 2048
#define SKV 2048
#define DMODEL 1024
#define HEADS 16
#define DH 64

typedef __bf16 bf8_t __attribute__((ext_vector_type(8)));
typedef float f4_t __attribute__((ext_vector_type(4)));
typedef float f16_t __attribute__((ext_vector_type(16)));
typedef unsigned int u32;
typedef unsigned short ush;

static __device__ __forceinline__ ush f2bf(float f) {
  __bf16 h = (__bf16)f;
  return __builtin_bit_cast(ush, h);
}
static __device__ __forceinline__ u32 pk2(float a, float b) {
  return (u32)f2bf(a) | ((u32)f2bf(b) << 16);
}
// async global->LDS, 16B per lane. dst = wave-uniform base; HW adds lane*16.
static __device__ __forceinline__ void async16(const ush* g, ush* l) {
  __builtin_amdgcn_global_load_lds((const __attribute__((address_space(1))) unsigned int*)g,
                                   (__attribute__((address_space(3))) unsigned int*)l, 16, 0, 0);
}
// raw barrier with compiler memory fences on both sides
static __device__ __forceinline__ void barrier_f() {
  asm volatile("" ::: "memory");
  __builtin_amdgcn_s_barrier();
  asm volatile("" ::: "memory");
}

// ---------------------------------------------------------------------------
// prep: fused activation cvt (blocks 0..8191) + weight transpose (8192..9215).
// ---------------------------------------------------------------------------
__global__ __launch_bounds__(256) void prep_k(const float* __restrict__ hs,
                                              const float* __restrict__ ehs,
                                              const float* __restrict__ W0,
                                              const float* __restrict__ W1,
                                              const float* __restrict__ W2,
                                              const float* __restrict__ W3,
                                              ush* __restrict__ wT,
                                              ush* __restrict__ hsb, ush* __restrict__ ehsb) {
  __shared__ ush t[64][72];
  const int bx = blockIdx.x;
  const int tid = threadIdx.x;
  if (bx < 8192) {
    const float* X = bx < 4096 ? hs : ehs;
    ush* Y = bx < 4096 ? hsb : ehsb;
    const size_t i = ((size_t)(bx & 4095) * 256 + tid) * 8;
    float4 a = *reinterpret_cast<const float4*>(X + i);
    float4 b = *reinterpret_cast<const float4*>(X + i + 4);
    uint4 u = {pk2(a.x, a.y), pk2(a.z, a.w), pk2(b.x, b.y), pk2(b.z, b.w)};
    *reinterpret_cast<uint4*>(Y + i) = u;
    return;
  }
  const int idx = bx - 8192;  // 0..1023
  const int z = idx >> 8, kb = (idx >> 4) & 15, nb = idx & 15;
  const float* W = z == 0 ? W0 : z == 1 ? W1 : z == 2 ? W2 : W3;
  const float scl = (z == 0) ? 0.125f * 1.44269504088896f : 1.0f;
  ush* o = wT + (size_t)z * (DMODEL * DMODEL);
  const int k0 = kb * 64, n0 = nb * 64;
#pragma unroll
  for (int it = 0; it < 4; ++it) {
    int c = tid + it * 256;
    int r = c >> 4, q4 = c & 15;
    float4 v = *reinterpret_cast<const float4*>(&W[(size_t)(k0 + r) * DMODEL + n0 + q4 * 4]);
    t[q4 * 4 + 0][r] = f2bf(v.x * scl);
    t[q4 * 4 + 1][r] = f2bf(v.y * scl);
    t[q4 * 4 + 2][r] = f2bf(v.z * scl);
    t[q4 * 4 + 3][r] = f2bf(v.w * scl);
  }
  __syncthreads();
#pragma unroll
  for (int it = 0; it < 2; ++it) {
    int c = tid + it * 256;
    int r = c >> 3, s8 = c & 7;
    uint4 pv;
    pv.x = (u32)t[r][s8 * 8 + 0] | ((u32)t[r][s8 * 8 + 1] << 16);
    pv.y = (u32)t[r][s8 * 8 + 2] | ((u32)t[r][s8 * 8 + 3] << 16);
    pv.z = (u32)t[r][s8 * 8 + 4] | ((u32)t[r][s8 * 8 + 5] << 16);
    pv.w = (u32)t[r][s8 * 8 + 6] | ((u32)t[r][s8 * 8 + 7] << 16);
    *reinterpret_cast<uint4*>(&o[(size_t)(n0 + r) * DMODEL + k0 + s8 * 8]) = pv;
  }
}

// ---------------------------------------------------------------------------
// Projection GEMM, 128x128 tile, BK=64, global_load_lds staging, double-
// buffered, counted vmcnt. NEW (T1): chunked bijective XCD swizzle — the 8
// n-neighbor blocks sharing one A-panel land on the SAME XCD (A fetched once
// per panel per L2; 2MB B-matrix becomes L2-resident per XCD).
//   0: A=hsb  -> Qb bf16 [row][col]
//   1: A=ehsb -> K2: attn read-order
//   2: A=ehsb -> V2: attn read-order
//   3: A=AO   -> out f32 + bias
// ---------------------------------------------------------------------------
__global__ __launch_bounds__(256, 2) void proj_k(const ush* __restrict__ hsb,
                                                 const ush* __restrict__ ehsb,
                                                 const ush* __restrict__ AO,
                                                 const ush* __restrict__ wT,
                                                 ush* __restrict__ Qb, ush* __restrict__ K2,
                                                 ush* __restrict__ V2, float* __restrict__ out,
                                                 const float* __restrict__ bias, int segbase) {
  __shared__ ush As[2][128 * 64];
  __shared__ ush Bs[2][128 * 64];
  const int tid = threadIdx.x;
  const int lane = tid & 63, w = tid >> 6;
  const int wr = w >> 1, wc = w & 1;
  const int lr = lane & 15, lg = lane >> 4;
  // chunked XCD swizzle (bijective; gridDim.x % 8 == 0 for both launches)
  const int bid0 = blockIdx.x;
  const int cpx = gridDim.x >> 3;  // blocks per XCD chunk
  const int bid = (bid0 & 7) * cpx + (bid0 >> 3);
  const int seg = segbase + (bid >> 9);
  const int t = bid & 511;
  const int m0 = (t >> 3) * 128, n0 = (t & 7) * 128;
  const ush* A = seg == 0 ? hsb : (seg == 3 ? AO : ehsb);
  const ush* BT = wT + (size_t)seg * (DMODEL * DMODEL);

  auto stage = [&](int bf, int kt) {
    const int kb = kt * 64;
#pragma unroll
    for (int ch = 0; ch < 4; ++ch) {
      const int g = ch * 256 + tid;
      const int r = g >> 3, s8 = (g & 7) ^ (r & 7);
      async16(A + (size_t)(m0 + r) * DMODEL + kb + s8 * 8, &As[bf][(ch * 256 + w * 64) * 8]);
      async16(BT + (size_t)(n0 + r) * DMODEL + kb + s8 * 8, &Bs[bf][(ch * 256 + w * 64) * 8]);
    }
  };

  f4_t acc[4][4] = {};
  stage(0, 0);
  for (int kt = 0; kt < DMODEL / 64; ++kt) {
    const int cur = kt & 1;
    barrier_f();
    if (kt + 1 < DMODEL / 64) {
      stage(cur ^ 1, kt + 1);
      asm volatile("s_waitcnt vmcnt(8)" ::: "memory");
    } else {
      asm volatile("s_waitcnt vmcnt(0)" ::: "memory");
    }
    barrier_f();
#pragma unroll
    for (int ks = 0; ks < 2; ++ks) {
      bf8_t a[4], b[4];
#pragma unroll
      for (int rf = 0; rf < 4; ++rf) {
        const int row = wr * 64 + rf * 16 + lr;
        a[rf] = *reinterpret_cast<const bf8_t*>(
            &As[cur][(row * 64 + ks * 32 + lg * 8) ^ ((row & 7) << 3)]);
      }
#pragma unroll
      for (int cf = 0; cf < 4; ++cf) {
        const int nn = wc * 64 + cf * 16 + lr;
        b[cf] = *reinterpret_cast<const bf8_t*>(
            &Bs[cur][(nn * 64 + ks * 32 + lg * 8) ^ ((nn & 7) << 3)]);
      }
      __builtin_amdgcn_s_setprio(1);
#pragma unroll
      for (int rf = 0; rf < 4; ++rf)
#pragma unroll
        for (int cf = 0; cf < 4; ++cf)
          acc[rf][cf] = __builtin_amdgcn_mfma_f32_16x16x32_bf16(a[rf], b[cf], acc[rf][cf], 0, 0, 0);
      __builtin_amdgcn_s_setprio(0);
    }
  }
  // Epilogue. C/D layout: col = lane&15, row = (lane>>4)*4 + i.
  if (seg == 1 || seg == 2) {
    ush* L = &As[0][0];
    barrier_f();
#pragma unroll
    for (int rf = 0; rf < 4; ++rf)
#pragma unroll
      for (int cf = 0; cf < 4; ++cf) {
        const int nl = wc * 64 + cf * 16 + lr;
        const int h2 = nl >> 6, dd = nl & 63;
#pragma unroll
        for (int i = 0; i < 4; ++i) {
          const int kvl = wr * 64 + rf * 16 + lg * 4 + i;
          const int kt2 = kvl >> 6, s = kvl & 63;
          int idx;
          if (seg == 1) {
            idx = ((h2 * 2 + kt2) << 12) + (((dd >> 4) * 2 + ((dd >> 3) & 1)) << 9) +
                  (s << 3) + (dd & 7);
          } else {
            idx = ((h2 * 2 + kt2) << 12) + (((s >> 4) * 2 + ((s >> 3) & 1)) << 9) +
                  (dd << 3) + (s & 7);
          }
          L[idx] = f2bf(acc[rf][cf][i]);
        }
      }
    barrier_f();
    ush* G = (seg == 1) ? K2 : V2;
    const int bb = m0 >> 11, kt0 = (m0 & 2047) >> 6;
    const int h0 = n0 >> 6;
#pragma unroll
    for (int j = 0; j < 4; ++j) {
      const size_t dst =
          ((size_t)(bb * 16 + h0 + (j >> 1)) * 32 + kt0 + (j & 1)) * 4096 + tid * 16;
      *reinterpret_cast<uint4*>(&G[dst]) =
          *reinterpret_cast<const uint4*>(&L[j * 4096 + tid * 16]);
      *reinterpret_cast<uint4*>(&G[dst + 8]) =
          *reinterpret_cast<const uint4*>(&L[j * 4096 + tid * 16 + 8]);
    }
  } else if (seg == 3) {
#pragma unroll
    for (int cf = 0; cf < 4; ++cf) {
      const int col = n0 + wc * 64 + cf * 16 + lr;
      const float bv = bias[col];
#pragma unroll
      for (int rf = 0; rf < 4; ++rf)
#pragma unroll
        for (int i = 0; i < 4; ++i) {
          const int row = m0 + wr * 64 + rf * 16 + lg * 4 + i;
          out[(size_t)row * DMODEL + col] = acc[rf][cf][i] + bv;
        }
    }
  } else {
#pragma unroll
    for (int rf = 0; rf < 4; ++rf)
#pragma unroll
      for (int cf = 0; cf < 4; ++cf)
#pragma unroll
        for (int i = 0; i < 4; ++i) {
          const int row = m0 + wr * 64 + rf * 16 + lg * 4 + i;
          const int col = n0 + wc * 64 + cf * 16 + lr;
          Qb[(size_t)row * DMODEL + col] = f2bf(acc[rf][cf][i]);
        }
  }
}

// ---------------------------------------------------------------------------
// Flash attention (swapped 32x32, D=64), zero-shift softmax, read-order K/V,
// MFMA ones-trick row-sum. (R12 configuration — best measured, 88.5 us.)
// ---------------------------------------------------------------------------
__global__ __launch_bounds__(256, 4) void attn_k(const ush* __restrict__ Qb,
                                                 const ush* __restrict__ K2,
                                                 const ush* __restrict__ V2,
                                                 ush* __restrict__ AO) {
  __shared__ ush Ks[2][4096];
  __shared__ ush Vs[2][4096];
  const int tid = threadIdx.x;
  const int lane = tid & 63, w = tid >> 6;
  const int rw = lane & 31, hi = lane >> 5;

  const int bid = blockIdx.x;
  const int swz = (bid & 7) * 128 + (bid >> 3);
  const int hl = swz >> 4;  // b*16+h
  const int qb = swz & 15;
  const int b = hl >> 4, h = hl & 15;
  const int q0 = qb * 128 + w * 32;

  const ush* Qp = Qb + ((size_t)(b * SQ + q0 + rw)) * DMODEL + h * DH + hi * 8;
  bf8_t qf[4];
#pragma unroll
  for (int f = 0; f < 4; ++f) qf[f] = *reinterpret_cast<const bf8_t*>(Qp + 16 * f);

  bf8_t ones;
#pragma unroll
  for (int i = 0; i < 8; ++i) ones[i] = __builtin_bit_cast(__bf16, (ush)0x3F80);

  f16_t acc0 = {}, acc1 = {}, sacc = {};

  const ush* Kh = K2 + (size_t)hl * 131072;  // 32 kt * 4096
  const ush* Vh = V2 + (size_t)hl * 131072;

  auto stage = [&](int bf, int kt) {  // 4 async16 per wave, pure linear copy
    const ush* ksrc = Kh + (size_t)kt * 4096;
    const ush* vsrc = Vh + (size_t)kt * 4096;
#pragma unroll
    for (int ch = 0; ch < 2; ++ch) {
      const int off = (ch * 256 + tid) * 8;
      async16(ksrc + off, &Ks[bf][(ch * 256 + w * 64) * 8]);
      async16(vsrc + off, &Vs[bf][(ch * 256 + w * 64) * 8]);
    }
  };

  stage(0, 0);
  int cur = 0;
  for (int kt = 0; kt < SKV / 64; ++kt) {
    barrier_f();
    if (kt + 1 < SKV / 64) {
      stage(cur ^ 1, kt + 1);
      asm volatile("s_waitcnt vmcnt(4)" ::: "memory");
    } else {
      asm volatile("s_waitcnt vmcnt(0)" ::: "memory");
    }
    barrier_f();

    // ---- QK^T: S^T[kv][q] (zero shift) ----
    f16_t s0 = {}, s1 = {};
    __builtin_amdgcn_s_setprio(1);
#pragma unroll
    for (int f = 0; f < 4; ++f) {
      const int base = (f * 128 + hi * 64 + rw) * 8;
      bf8_t k0 = *reinterpret_cast<const bf8_t*>(&Ks[cur][base]);
      bf8_t k1 = *reinterpret_cast<const bf8_t*>(&Ks[cur][base + 256]);
      s0 = __builtin_amdgcn_mfma_f32_32x32x16_bf16(k0, qf[f], s0, 0, 0, 0);
      s1 = __builtin_amdgcn_mfma_f32_32x32x16_bf16(k1, qf[f], s1, 0, 0, 0);
    }
    __builtin_amdgcn_s_setprio(0);

    // ---- P = exp2(S) ----
#pragma unroll
    for (int i = 0; i < 16; ++i) s0[i] = __builtin_amdgcn_exp2f(s0[i]);
#pragma unroll
    for (int i = 0; i < 16; ++i) s1[i] = __builtin_amdgcn_exp2f(s1[i]);

    // ---- PV: O^T += V^T x P; row-sum via MFMA ones-trick ----
    __builtin_amdgcn_s_setprio(1);
#pragma unroll
    for (int kb = 0; kb < 2; ++kb) {
      const f16_t& sv = kb ? s1 : s0;
      bf8_t pf[2];
      {
        u32 w0 = pk2(sv[0], sv[1]), w2 = pk2(sv[4], sv[5]);
        asm volatile("v_permlane32_swap_b32 %0, %1" : "+v"(w0), "+v"(w2));
        u32 w1 = pk2(sv[2], sv[3]), w3 = pk2(sv[6], sv[7]);
        asm volatile("v_permlane32_swap_b32 %0, %1" : "+v"(w1), "+v"(w3));
        uint4 t0 = {w0, w1, w2, w3};
        pf[0] = __builtin_bit_cast(bf8_t, t0);
        u32 x0 = pk2(sv[8], sv[9]), x2 = pk2(sv[12], sv[13]);
        asm volatile("v_permlane32_swap_b32 %0, %1" : "+v"(x0), "+v"(x2));
        u32 x1 = pk2(sv[10], sv[11]), x3 = pk2(sv[14], sv[15]);
        asm volatile("v_permlane32_swap_b32 %0, %1" : "+v"(x1), "+v"(x3));
        uint4 t1 = {x0, x1, x2, x3};
        pf[1] = __builtin_bit_cast(bf8_t, t1);
      }
#pragma unroll
      for (int s = 0; s < 2; ++s) {
        const int vbase = ((2 * kb + s) * 128 + hi * 64 + rw) * 8;
        bf8_t v0 = *reinterpret_cast<const bf8_t*>(&Vs[cur][vbase]);
        bf8_t v1 = *reinterpret_cast<const bf8_t*>(&Vs[cur][vbase + 256]);
        acc0 = __builtin_amdgcn_mfma_f32_32x32x16_bf16(v0, pf[s], acc0, 0, 0, 0);
        acc1 = __builtin_amdgcn_mfma_f32_32x32x16_bf16(v1, pf[s], acc1, 0, 0, 0);
        sacc = __builtin_amdgcn_mfma_f32_32x32x16_bf16(ones, pf[s], sacc, 0, 0, 0);
      }
    }
    __builtin_amdgcn_s_setprio(0);
    cur ^= 1;
  }

  const float inv = 1.f / sacc[0];
  ush* Op = AO + ((size_t)(b * SQ + q0 + rw)) * DMODEL + h * DH;
#pragma unroll
  for (int db = 0; db < 2; ++db) {
    const f16_t& A = db ? acc1 : acc0;
#pragma unroll
    for (int r = 0; r < 16; r += 2) {
      const int d = db * 32 + (r & 3) + 8 * (r >> 2) + 4 * hi;
      *reinterpret_cast<u32*>(Op + d) = pk2(A[r] * inv, A[r + 1] * inv);
    }
  }
}

// ---------------------------------------------------------------------------
extern "C" void kernel_launch(void* const* d_in, const int* in_sizes, int n_in,
                              void* d_out, int out_size, void* d_ws, size_t ws_size,
                              hipStream_t stream) {
  const float* hs = (const float*)d_in[0];
  const float* ehs = (const float*)d_in[1];
  const float* Wq = (const float*)d_in[2];
  const float* Wk = (const float*)d_in[3];
  const float* Wv = (const float*)d_in[4];
  const float* Wo = (const float*)d_in[5];
  const float* bo = (const float*)d_in[6];
  float* out = (float*)d_out;

  unsigned short* ws = (unsigned short*)d_ws;
  const size_t MM = (size_t)1024 * 1024;
  unsigned short* wT = ws;            // 4 MM: WqT(scaled), WkT, WvT, WoT (bf16 [N][K])
  unsigned short* Qb = ws + 4 * MM;   // 8 MM: Q bf16 [row][col]
  unsigned short* K2 = Qb + 8 * MM;   // 8 MM: K bf16, attn read-order
  unsigned short* V2 = K2 + 8 * MM;   // 8 MM: V bf16, attn read-order
  unsigned short* AO = V2 + 8 * MM;   // 8 MM: attn out bf16
  // bf16 activations live inside d_out (32 MB); consumed before final GEMM.
  unsigned short* hsb = (unsigned short*)d_out;  // 8 MM
  unsigned short* ehsb = hsb + 8 * MM;           // 8 MM

  prep_k<<<dim3(9216), 256, 0, stream>>>(hs, ehs, Wq, Wk, Wv, Wo, wT, hsb, ehsb);
  proj_k<<<dim3(1536), 256, 0, stream>>>(hsb, ehsb, AO, wT, Qb, K2, V2, out, bo, 0);
  attn_k<<<dim3(1024), 256, 0, stream>>>(Qb, K2, V2, AO);
  proj_k<<<dim3(512), 256, 0, stream>>>(hsb, ehsb, AO, wT, Qb, K2, V2, out, bo, 3);
}